// Round 1
// baseline (227.826 us; speedup 1.0000x reference)
//
#include <hip/hip_runtime.h>
#include <hip/hip_bf16.h>

typedef __bf16 bf16x8 __attribute__((ext_vector_type(8)));
typedef __bf16 bf16x4 __attribute__((ext_vector_type(4)));
typedef float  f32x16 __attribute__((ext_vector_type(16)));

#define GPTR(p) ((__attribute__((address_space(1))) void*)(p))
#define LPTR(p) ((__attribute__((address_space(3))) void*)(p))

// ---------------------------------------------------------------------------
// D1: cvt F_w (512) | transpose-cvt G_w (256) | gemv b2 = F_w@G_b + F_b (1024)
// ---------------------------------------------------------------------------
__global__ __launch_bounds__(256) void pre_kernel(
    const float* __restrict__ Fw, __bf16* __restrict__ f_bf,
    const float* __restrict__ Gw, __bf16* __restrict__ gt_bf,
    const float* __restrict__ Gb, const float* __restrict__ Fb,
    float* __restrict__ b2, int H) {
    __shared__ float tile[64][65];
    const int blk = blockIdx.x;
    const int t = threadIdx.x;

    if (blk < 512) {                       // cvt F_w
        long i = ((long)blk * 256 + t) * 8;
        float4 a = *reinterpret_cast<const float4*>(Fw + i);
        float4 c = *reinterpret_cast<const float4*>(Fw + i + 4);
        bf16x8 o;
        o[0] = (__bf16)a.x; o[1] = (__bf16)a.y; o[2] = (__bf16)a.z; o[3] = (__bf16)a.w;
        o[4] = (__bf16)c.x; o[5] = (__bf16)c.y; o[6] = (__bf16)c.z; o[7] = (__bf16)c.w;
        *reinterpret_cast<bf16x8*>(f_bf + i) = o;
    } else if (blk < 768) {                // transpose-cvt G_w: gt[k][h] = G[h][k]
        const int id = blk - 512;
        const int bx = (id & 15) * 64;
        const int by = (id >> 4) * 64;
        const int tr = t >> 4;
        const int tc = (t & 15) * 4;
#pragma unroll
        for (int i = 0; i < 4; i++) {
            float4 v = *reinterpret_cast<const float4*>(&Gw[(size_t)(by + tr + i * 16) * H + bx + tc]);
            tile[tr + i * 16][tc + 0] = v.x;
            tile[tr + i * 16][tc + 1] = v.y;
            tile[tr + i * 16][tc + 2] = v.z;
            tile[tr + i * 16][tc + 3] = v.w;
        }
        __syncthreads();
        const int wr = t >> 2;
        const int wc = (t & 3) * 16;
        bf16x8 o0, o1;
#pragma unroll
        for (int j = 0; j < 8; j++) o0[j] = (__bf16)tile[wc + j][wr];
#pragma unroll
        for (int j = 0; j < 8; j++) o1[j] = (__bf16)tile[wc + 8 + j][wr];
        *reinterpret_cast<bf16x8*>(&gt_bf[(size_t)(bx + wr) * H + by + wc]) = o0;
        *reinterpret_cast<bf16x8*>(&gt_bf[(size_t)(bx + wr) * H + by + wc + 8]) = o1;
    } else {                               // gemv b2[o] = Fw[o,:]·Gb + Fb[o]
        const int o = blk - 768;
        float s = 0.f;
        for (int h = t; h < H; h += 256) s += Fw[(size_t)o * H + h] * Gb[h];
#pragma unroll
        for (int off = 32; off > 0; off >>= 1) s += __shfl_xor(s, off);
        __shared__ float ss[4];
        if ((t & 63) == 0) ss[t >> 6] = s;
        __syncthreads();
        if (t == 0) b2[o] = ss[0] + ss[1] + ss[2] + ss[3] + Fb[o];
    }
}

// ---------------------------------------------------------------------------
// D2: GEMM0 W=F·Gt (0..255) | transpose-cvt hidden -> Xt[b][h][s] (256..2303)
//     | wave-per-row softmax (2304..4351; 4 rows/block, no LDS, shfl-only)
// LDS: union of GEMM0 tiles and transpose tile (16.6 KB, was 32.5 -> occup up)
// ---------------------------------------------------------------------------
union MidSmem {
    struct { __bf16 a[64 * 64]; __bf16 b[64 * 64]; } g;
    float tile[64][65];
};

__global__ __launch_bounds__(256) void mid_kernel(
    const __bf16* __restrict__ f_bf, const __bf16* __restrict__ gt_bf,
    __bf16* __restrict__ Wm,
    const float* __restrict__ hidden, __bf16* __restrict__ xt,
    const float* __restrict__ R, const float* __restrict__ mask,
    __bf16* __restrict__ P, int H, int S) {
    __shared__ __align__(16) MidSmem sm;
    const int blk = blockIdx.x;
    const int t = threadIdx.x;

    if (blk < 256) {  // GEMM0 64x64 tile: direct write Wm[o][k]
        __bf16* As = sm.g.a;
        __bf16* Bs = sm.g.b;
        const int lane = t & 63;
        const int wave = t >> 6;
        const int lane31 = lane & 31;
        const int hi = lane >> 5;
        const int wm = (wave >> 1) * 32;
        const int wn = (wave & 1) * 32;
        const int bm = (blk >> 4) * 64;
        const int bn = (blk & 15) * 64;

        const int rsub = lane >> 3;
        const int csub = lane & 7;
        const int lchunk = csub ^ rsub;
        const __bf16* ga0 = f_bf + (size_t)(bm + wave * 16 + rsub) * H + lchunk * 8;
        const __bf16* gb0 = gt_bf + (size_t)(bn + wave * 16 + rsub) * H + lchunk * 8;

        f32x16 acc = (f32x16)(0.f);
        for (int kt = 0; kt < H; kt += 64) {
            __syncthreads();
#pragma unroll
            for (int c = 0; c < 2; c++)
                __builtin_amdgcn_global_load_lds(GPTR(ga0 + (size_t)(c * 8) * H + kt),
                                                 LPTR(&As[(wave * 16 + c * 8) * 64]), 16, 0, 0);
#pragma unroll
            for (int c = 0; c < 2; c++)
                __builtin_amdgcn_global_load_lds(GPTR(gb0 + (size_t)(c * 8) * H + kt),
                                                 LPTR(&Bs[(wave * 16 + c * 8) * 64]), 16, 0, 0);
            __syncthreads();
#pragma unroll
            for (int s = 0; s < 4; s++) {
                const int ra = wm + lane31;
                const int rb = wn + lane31;
                bf16x8 af = *reinterpret_cast<const bf16x8*>(
                    &As[ra * 64 + (((2 * s + hi) ^ (ra & 7)) << 3)]);
                bf16x8 bfr = *reinterpret_cast<const bf16x8*>(
                    &Bs[rb * 64 + (((2 * s + hi) ^ (rb & 7)) << 3)]);
                acc = __builtin_amdgcn_mfma_f32_32x32x16_bf16(af, bfr, acc, 0, 0, 0);
            }
        }
        const int cm = bm + wm;
        const int cn = bn + wn + lane31;
#pragma unroll
        for (int rq = 0; rq < 4; rq++) {
            const int rbase = rq * 8 + 4 * hi;
#pragma unroll
            for (int rr = 0; rr < 4; rr++)
                Wm[(size_t)(cm + rbase + rr) * H + cn] = (__bf16)acc[rq * 4 + rr];
        }
    } else if (blk < 2304) {  // transpose-cvt hidden[b]: Xt[b][h][s]
        const int id = blk - 256;
        const int b = id >> 9;
        const int tid = id & 511;
        const int by = (tid >> 4) * 64;    // s-base
        const int bx = (tid & 15) * 64;    // h-base
        const float* x = hidden + (size_t)b * S * H;
        __bf16* y = xt + (size_t)b * H * S;
        const int tr = t >> 4;
        const int tc = (t & 15) * 4;
#pragma unroll
        for (int i = 0; i < 4; i++) {
            float4 v = *reinterpret_cast<const float4*>(&x[(size_t)(by + tr + i * 16) * H + bx + tc]);
            sm.tile[tr + i * 16][tc + 0] = v.x;
            sm.tile[tr + i * 16][tc + 1] = v.y;
            sm.tile[tr + i * 16][tc + 2] = v.z;
            sm.tile[tr + i * 16][tc + 3] = v.w;
        }
        __syncthreads();
        const int wr = t >> 2;
        const int wc = (t & 3) * 16;
        bf16x8 o0, o1;
#pragma unroll
        for (int j = 0; j < 8; j++) o0[j] = (__bf16)sm.tile[wc + j][wr];
#pragma unroll
        for (int j = 0; j < 8; j++) o1[j] = (__bf16)sm.tile[wc + 8 + j][wr];
        *reinterpret_cast<bf16x8*>(&y[(size_t)(bx + wr) * S + by + wc]) = o0;
        *reinterpret_cast<bf16x8*>(&y[(size_t)(bx + wr) * S + by + wc + 8]) = o1;
    } else {          // softmax: one wave per row, 32 elems/lane, shuffle-only
        const int id = blk - 2304;         // 0..2047
        const int lane = t & 63, wave = t >> 6;
        const int row = id * 4 + wave;     // 0..8191
        const int b = row >> 11;
        const int q = row & 2047;
        const float* rrow = R + (size_t)q * S;
        const float* mrow = mask + ((size_t)b * S + q) * (size_t)S;
        __bf16* prow = P + ((size_t)b * S + q) * (size_t)S;

        float v[32];
#pragma unroll
        for (int i = 0; i < 8; i++) {
            float4 r4 = *reinterpret_cast<const float4*>(rrow + i * 256 + lane * 4);
            float4 m4 = *reinterpret_cast<const float4*>(mrow + i * 256 + lane * 4);
            v[i * 4 + 0] = r4.x + m4.x;
            v[i * 4 + 1] = r4.y + m4.y;
            v[i * 4 + 2] = r4.z + m4.z;
            v[i * 4 + 3] = r4.w + m4.w;
        }
        float mx = v[0];
#pragma unroll
        for (int i = 1; i < 32; i++) mx = fmaxf(mx, v[i]);
#pragma unroll
        for (int off = 32; off > 0; off >>= 1) mx = fmaxf(mx, __shfl_xor(mx, off));
        float sum = 0.f;
#pragma unroll
        for (int i = 0; i < 32; i++) { v[i] = __expf(v[i] - mx); sum += v[i]; }
#pragma unroll
        for (int off = 32; off > 0; off >>= 1) sum += __shfl_xor(sum, off);
        const float inv = 1.0f / sum;
#pragma unroll
        for (int i = 0; i < 8; i++) {
            bf16x4 o;
#pragma unroll
            for (int j = 0; j < 4; j++) o[j] = (__bf16)(v[i * 4 + j] * inv);
            *reinterpret_cast<bf16x4*>(prow + i * 256 + lane * 4) = o;
        }
    }
}

// ---------------------------------------------------------------------------
// Phase-split NT GEMM (T3+T4+T5): C[m,n] = sum_k A[m,k]*B[n,k] (+ bias[n])
// Tile 256x128, BK=64, 512 thr = 8 waves (4m x 2n of 64x64), grid 256 = 1/CU.
// TRIPLE-buffered LDS (3 x 48 KB = 144 KB): stage tile t+2 during iter t, so
// the end-of-iter wait is vmcnt(6) (tile t+2's 6 DMAs stay in flight), never
// a full drain except at the tail. 4 phases/iter, each:
//   {ds_read 0/4/8 b128 | issue 2 global_load_lds} -> s_barrier ->
//   lgkmcnt(0) -> setprio(1) -> 4 MFMA (one acc quadrant) -> setprio(0) -> bar
// Quadrant order 00,01,11,10 reuses a0/b0/a1/b1 regs: 16 ds_read/iter total.
// Staging keeps the proven XOR-chunk involution (src chunk = csub^rsub,
// linear LDS dest, ds_read chunk = (2s+hi)^(row&7)).
// Row m-tiles are 256 rows -> batch = bm>>11 selects B panel (strideB=0 for
// the W gemm). XCD swizzle: id&7 -> 4 consecutive m-tiles per XCD.
// ---------------------------------------------------------------------------
template <bool CFLOAT, bool BIAS>
__global__ __launch_bounds__(512, 2) void gemm8_nt(
    const __bf16* __restrict__ A, const __bf16* __restrict__ B,
    const float* __restrict__ bias, void* __restrict__ Cv,
    int K, int lda, int ldb, int ldc, long strideB) {
    const int t = threadIdx.x;
    const int lane = t & 63;
    const int wave = t >> 6;             // 0..7
    const int lane31 = lane & 31;
    const int hi = lane >> 5;
    const int wm = (wave >> 1) * 64;     // 0,64,128,192
    const int wn = (wave & 1) * 64;      // 0,64

    const int id = blockIdx.x;           // 256 blocks
    const int xcd = id & 7;
    const int slot = id >> 3;            // 0..31
    const int bm = (xcd * 4 + (slot >> 3)) * 256;
    const int bn = (slot & 7) * 128;
    B += (size_t)(bm >> 11) * strideB;   // batch select (2048 rows/batch)

    __shared__ __align__(16) __bf16 smem[3 * 24576];   // 144 KB

    const int rsub = lane >> 3;
    const int csub = lane & 7;
    const int lchunk = csub ^ rsub;
    // wave stages A rows wave*32..+31 (4 DMAs), B rows wave*16..+15 (2 DMAs)
    const __bf16* ga0 = A + (size_t)(bm + wave * 32 + rsub) * lda + lchunk * 8;
    const __bf16* gb0 = B + (size_t)(bn + wave * 16 + rsub) * ldb + lchunk * 8;

    auto stageA = [&](int p, int kt, int c) {
        __builtin_amdgcn_global_load_lds(GPTR(ga0 + (size_t)(c * 8) * lda + kt),
                                         LPTR(&smem[p * 24576 + (wave * 32 + c * 8) * 64]), 16, 0, 0);
    };
    auto stageBv = [&](int p, int kt, int c) {
        __builtin_amdgcn_global_load_lds(GPTR(gb0 + (size_t)(c * 8) * ldb + kt),
                                         LPTR(&smem[p * 24576 + 16384 + (wave * 16 + c * 8) * 64]), 16, 0, 0);
    };

    f32x16 acc[2][2];
#pragma unroll
    for (int i = 0; i < 2; i++)
#pragma unroll
        for (int j = 0; j < 2; j++) acc[i][j] = (f32x16)(0.f);

    const int nt = K >> 6;
    // prologue: stage tiles 0 and 1 (grouped per tile -> FIFO vmcnt counting)
#pragma unroll
    for (int c = 0; c < 4; c++) stageA(0, 0, c);
#pragma unroll
    for (int c = 0; c < 2; c++) stageBv(0, 0, c);
#pragma unroll
    for (int c = 0; c < 4; c++) stageA(1, 64, c);
#pragma unroll
    for (int c = 0; c < 2; c++) stageBv(1, 64, c);
    asm volatile("s_waitcnt vmcnt(6)" ::: "memory");   // tile 0 resident
    __builtin_amdgcn_s_barrier();

    const int ra0 = wm + lane31;
    const int ra1 = wm + 32 + lane31;
    const int rb0 = wn + lane31;
    const int rb1 = wn + 32 + lane31;
    const int ca = lane31 & 7;

    int cur = 0;
    for (int it = 0; it < nt; ++it) {
        const __bf16* As = smem + cur * 24576;
        const __bf16* Bs = smem + cur * 24576 + 16384;
        const int kt2 = (it + 2) << 6;
        const bool pre = (it + 2) < nt;
        const int p2 = (cur >= 1) ? cur - 1 : 2;     // (cur+2)%3
        bf16x8 a0[4], a1[4], b0[4], b1[4];

        // phase 0: read a0,b0 -> acc[0][0]
#pragma unroll
        for (int s = 0; s < 4; s++) {
            a0[s] = *reinterpret_cast<const bf16x8*>(&As[ra0 * 64 + (((2 * s + hi) ^ ca) << 3)]);
            b0[s] = *reinterpret_cast<const bf16x8*>(&Bs[rb0 * 64 + (((2 * s + hi) ^ ca) << 3)]);
        }
        __builtin_amdgcn_s_barrier();
        asm volatile("s_waitcnt lgkmcnt(0)");
        __builtin_amdgcn_s_setprio(1);
#pragma unroll
        for (int s = 0; s < 4; s++)
            acc[0][0] = __builtin_amdgcn_mfma_f32_32x32x16_bf16(a0[s], b0[s], acc[0][0], 0, 0, 0);
        __builtin_amdgcn_s_setprio(0);
        __builtin_amdgcn_s_barrier();

        // phase 1: read b1; issue A c0,c1 for tile it+2 -> acc[0][1]
#pragma unroll
        for (int s = 0; s < 4; s++)
            b1[s] = *reinterpret_cast<const bf16x8*>(&Bs[rb1 * 64 + (((2 * s + hi) ^ ca) << 3)]);
        if (pre) { stageA(p2, kt2, 0); stageA(p2, kt2, 1); }
        __builtin_amdgcn_s_barrier();
        asm volatile("s_waitcnt lgkmcnt(0)");
        __builtin_amdgcn_s_setprio(1);
#pragma unroll
        for (int s = 0; s < 4; s++)
            acc[0][1] = __builtin_amdgcn_mfma_f32_32x32x16_bf16(a0[s], b1[s], acc[0][1], 0, 0, 0);
        __builtin_amdgcn_s_setprio(0);
        __builtin_amdgcn_s_barrier();

        // phase 2: read a1; issue A c2,c3 -> acc[1][1]
#pragma unroll
        for (int s = 0; s < 4; s++)
            a1[s] = *reinterpret_cast<const bf16x8*>(&As[ra1 * 64 + (((2 * s + hi) ^ ca) << 3)]);
        if (pre) { stageA(p2, kt2, 2); stageA(p2, kt2, 3); }
        __builtin_amdgcn_s_barrier();
        asm volatile("s_waitcnt lgkmcnt(0)");
        __builtin_amdgcn_s_setprio(1);
#pragma unroll
        for (int s = 0; s < 4; s++)
            acc[1][1] = __builtin_amdgcn_mfma_f32_32x32x16_bf16(a1[s], b1[s], acc[1][1], 0, 0, 0);
        __builtin_amdgcn_s_setprio(0);
        __builtin_amdgcn_s_barrier();

        // phase 3: issue B c0,c1; counted wait (tile it+1 resident) -> acc[1][0]
        if (pre) { stageBv(p2, kt2, 0); stageBv(p2, kt2, 1); }
        if (it + 1 < nt) {
            if (pre) asm volatile("s_waitcnt vmcnt(6)" ::: "memory");
            else     asm volatile("s_waitcnt vmcnt(0)" ::: "memory");
        }
        __builtin_amdgcn_s_barrier();
        __builtin_amdgcn_s_setprio(1);
#pragma unroll
        for (int s = 0; s < 4; s++)
            acc[1][0] = __builtin_amdgcn_mfma_f32_32x32x16_bf16(a1[s], b0[s], acc[1][0], 0, 0, 0);
        __builtin_amdgcn_s_setprio(0);
        cur = (cur == 2) ? 0 : cur + 1;
    }

    // Epilogue. C/D: col = lane&31, row = (reg&3)+8*(reg>>2)+4*(lane>>5)
    __bf16* Cb = (__bf16*)Cv;
    float* Cf = (float*)Cv;
#pragma unroll
    for (int mi = 0; mi < 2; mi++)
#pragma unroll
        for (int ni = 0; ni < 2; ni++) {
            const int cm = bm + wm + mi * 32;
            const int cn = bn + wn + ni * 32 + lane31;
            const float bv = BIAS ? bias[cn] : 0.0f;
#pragma unroll
            for (int rq = 0; rq < 4; rq++) {
                const int rbase = rq * 8 + 4 * hi;
                if constexpr (CFLOAT) {
#pragma unroll
                    for (int rr = 0; rr < 4; rr++)
                        Cf[(size_t)(cm + rbase + rr) * ldc + cn] = acc[mi][ni][rq * 4 + rr] + bv;
                } else {
#pragma unroll
                    for (int rr = 0; rr < 4; rr++)
                        Cb[(size_t)(cm + rbase + rr) * ldc + cn] = (__bf16)(acc[mi][ni][rq * 4 + rr] + bv);
                }
            }
        }
}

// ---------------------------------------------------------------------------
// Pipeline (out = (P @ X) W^T + b2, W = F G, b2 = F G_b + F_b):
//   D1[cvtF|transpG|gemv] -> D2[GEMM0->W || transp-hidden || softmax]
//   -> T1 = P @ Xt (bf16, M flattened to 8192) -> T2 = T1 @ W^T + b2 (fp32)
// ---------------------------------------------------------------------------
extern "C" void kernel_launch(void* const* d_in, const int* in_sizes, int n_in,
                              void* d_out, int out_size, void* d_ws, size_t ws_size,
                              hipStream_t stream) {
    const float* hidden = (const float*)d_in[0];
    const float* mask   = (const float*)d_in[1];
    const float* R      = (const float*)d_in[2];
    const float* G_w    = (const float*)d_in[3];
    const float* G_b    = (const float*)d_in[4];
    const float* F_w    = (const float*)d_in[5];
    const float* F_b    = (const float*)d_in[6];
    float* out = (float*)d_out;

    constexpr int B = 4, S = 2048, H = 1024;
    char* ws = (char*)d_ws;
    __bf16* xt    = (__bf16*)(ws);                   // 16 MB  Xt[b][h][s]
    __bf16* t1    = (__bf16*)(ws + (16ll << 20));    // 16 MB  T1[m][h]
    __bf16* probs = (__bf16*)(ws + (32ll << 20));    // 32 MB  P[m][s]
    __bf16* f_bf  = (__bf16*)(ws + (64ll << 20));    // 2 MB
    __bf16* gt_bf = (__bf16*)(ws + (66ll << 20));    // 2 MB
    __bf16* Wm    = (__bf16*)(ws + (68ll << 20));    // 2 MB
    float*  b2    = (float*)(ws + (70ll << 20));     // 4 KB

    pre_kernel<<<1792, 256, 0, stream>>>(F_w, f_bf, G_w, gt_bf, G_b, F_b, b2, H);

    mid_kernel<<<4352, 256, 0, stream>>>(f_bf, gt_bf, Wm, hidden, xt,
                                         R, mask, probs, H, S);

    // T1[m][h] = sum_s P[m][s] * Xt[b(m)][h][s]   (bf16 out)
    gemm8_nt<false, false><<<256, 512, 0, stream>>>(
        probs, xt, nullptr, t1, S, S, S, H, (long)H * S);

    // out[m][o] = sum_h T1[m][h] * W[o][h] + b2[o]   (fp32 out)
    gemm8_nt<true, true><<<256, 512, 0, stream>>>(
        t1, Wm, b2, out, H, H, H, H, 0);
}